// Round 1
// baseline (1076.113 us; speedup 1.0000x reference)
//
#include <hip/hip_runtime.h>
#include <hip/hip_bf16.h>
#include <math.h>

#define N_NODES 100000
#define N_EDGES 3200000
#define NFEAT 512
#define NHID 256
#define NCLASS 40
#define LDP 40   // padded LDS row stride in bf16 elems (80B -> 2-way bank aliasing, free)

typedef short bf16x8 __attribute__((ext_vector_type(8)));
typedef float f32x4 __attribute__((ext_vector_type(4)));

__device__ __forceinline__ unsigned short f2bf(float f) {
    unsigned int u = __builtin_bit_cast(unsigned int, f);
    u += 0x7fffu + ((u >> 16) & 1u);           // round-to-nearest-even
    return (unsigned short)(u >> 16);
}
__device__ __forceinline__ float bflo(unsigned int u) { return __builtin_bit_cast(float, u << 16); }
__device__ __forceinline__ float bfhi(unsigned int u) { return __builtin_bit_cast(float, u & 0xffff0000u); }

// ---------------- CSR build ----------------
__global__ void k_hist(const int* __restrict__ row, int* __restrict__ counts, int n) {
    int e = blockIdx.x * 256 + threadIdx.x;
    if (e < n) atomicAdd(&counts[row[e]], 1);
}

__global__ __launch_bounds__(256) void k_scanA(const int* __restrict__ counts, int* __restrict__ rowptr,
                                               int* __restrict__ bsums, int n) {
    __shared__ int sd[256];
    int t = threadIdx.x;
    int base = blockIdx.x * 1024 + t * 4;
    int v0 = (base + 0 < n) ? counts[base + 0] : 0;
    int v1 = (base + 1 < n) ? counts[base + 1] : 0;
    int v2 = (base + 2 < n) ? counts[base + 2] : 0;
    int v3 = (base + 3 < n) ? counts[base + 3] : 0;
    int s = v0 + v1 + v2 + v3;
    sd[t] = s;
    __syncthreads();
    for (int off = 1; off < 256; off <<= 1) {
        int x = (t >= off) ? sd[t - off] : 0;
        __syncthreads();
        sd[t] += x;
        __syncthreads();
    }
    int excl = sd[t] - s;
    if (base + 0 < n) rowptr[base + 0] = excl;
    if (base + 1 < n) rowptr[base + 1] = excl + v0;
    if (base + 2 < n) rowptr[base + 2] = excl + v0 + v1;
    if (base + 3 < n) rowptr[base + 3] = excl + v0 + v1 + v2;
    if (t == 255) bsums[blockIdx.x] = sd[255];
}

__global__ __launch_bounds__(128) void k_scanB(int* __restrict__ bsums, int* __restrict__ rowptr,
                                               int nblocks, int n) {
    __shared__ int sd[128];
    int t = threadIdx.x;
    int v = (t < nblocks) ? bsums[t] : 0;
    sd[t] = v;
    __syncthreads();
    for (int off = 1; off < 128; off <<= 1) {
        int x = (t >= off) ? sd[t - off] : 0;
        __syncthreads();
        sd[t] += x;
        __syncthreads();
    }
    if (t < nblocks) bsums[t] = sd[t] - v;   // exclusive block offset
    if (t == 127) rowptr[n] = sd[127];       // grand total
}

__global__ __launch_bounds__(256) void k_scanC(int* __restrict__ rowptr, int* __restrict__ cursor,
                                               const int* __restrict__ bsums, int n) {
    int t = threadIdx.x;
    int base = blockIdx.x * 1024 + t * 4;
    int off = bsums[blockIdx.x];
#pragma unroll
    for (int i = 0; i < 4; ++i) {
        int idx = base + i;
        if (idx < n) { int r = rowptr[idx] + off; rowptr[idx] = r; cursor[idx] = r; }
    }
}

__global__ void k_scatter(const int* __restrict__ row, const int* __restrict__ col,
                          const float* __restrict__ val, int* __restrict__ cursor,
                          int* __restrict__ pcol, float* __restrict__ pval, int n) {
    int e = blockIdx.x * 256 + threadIdx.x;
    if (e < n) {
        int r = row[e];
        int pos = atomicAdd(&cursor[r], 1);
        pcol[pos] = col[e];
        pval[pos] = val[e];
    }
}

// ---------------- weight transpose + bf16 convert ----------------
__global__ void k_w1t(const float* __restrict__ W1, unsigned short* __restrict__ W1T) {
    int i = blockIdx.x * 256 + threadIdx.x;   // NHID*NFEAT
    int nn = i >> 9, k = i & 511;
    W1T[i] = f2bf(W1[k * NHID + nn]);
}
__global__ void k_w2t(const float* __restrict__ W2, unsigned short* __restrict__ W2T) {
    int i = blockIdx.x * 256 + threadIdx.x;   // 64*NHID
    int nn = i >> 8, k = i & 255;
    W2T[i] = (nn < NCLASS) ? f2bf(W2[k * NCLASS + nn]) : (unsigned short)0;
}

// ---------------- GEMM1: support = bf16(x) @ bf16(W1), out bf16 ----------------
__global__ __launch_bounds__(256) void k_gemm1(const float* __restrict__ X,
                                               const unsigned short* __restrict__ W1T,
                                               unsigned short* __restrict__ support) {
    __shared__ unsigned short As[128 * LDP];
    __shared__ unsigned short Bs[128 * LDP];
    const int t = threadIdx.x;
    const int lane = t & 63;
    const int w = t >> 6;
    const int wm = w >> 1, wn = w & 1;
    const int l15 = lane & 15, l4 = lane >> 4;
    const int bm = blockIdx.x, bn = blockIdx.y;

    f32x4 acc[4][4];
#pragma unroll
    for (int m = 0; m < 4; ++m)
#pragma unroll
        for (int n = 0; n < 4; ++n) acc[m][n] = (f32x4){0.f, 0.f, 0.f, 0.f};

    const int srow = t >> 1;
    const int shalf = t & 1;
    const long grow = (long)bm * 128 + srow;
    const bool avalid = grow < N_NODES;
    const float* xsrc = X + grow * NFEAT + shalf * 16;
    const unsigned short* bsrc = W1T + ((long)bn * 128 + srow) * NFEAT + shalf * 16;
    unsigned short* adst = &As[srow * LDP + shalf * 16];
    unsigned short* bdst = &Bs[srow * LDP + shalf * 16];

    for (int kt = 0; kt < NFEAT; kt += 32) {
        union { float4 v4[4]; float f[16]; } a;
        if (avalid) {
            a.v4[0] = *(const float4*)(xsrc + kt + 0);
            a.v4[1] = *(const float4*)(xsrc + kt + 4);
            a.v4[2] = *(const float4*)(xsrc + kt + 8);
            a.v4[3] = *(const float4*)(xsrc + kt + 12);
        } else {
#pragma unroll
            for (int j = 0; j < 4; ++j) a.v4[j] = make_float4(0.f, 0.f, 0.f, 0.f);
        }
        union { uint4 q[2]; unsigned short us[16]; } u;
#pragma unroll
        for (int j = 0; j < 16; ++j) u.us[j] = f2bf(a.f[j]);
        uint4 b0 = *(const uint4*)(bsrc + kt);
        uint4 b1v = *(const uint4*)(bsrc + kt + 8);
        *(uint4*)(adst) = u.q[0];
        *(uint4*)(adst + 8) = u.q[1];
        *(uint4*)(bdst) = b0;
        *(uint4*)(bdst + 8) = b1v;
        __syncthreads();

        bf16x8 afr[4], bfr[4];
#pragma unroll
        for (int m = 0; m < 4; ++m)
            afr[m] = *(const bf16x8*)&As[(wm * 64 + m * 16 + l15) * LDP + l4 * 8];
#pragma unroll
        for (int n = 0; n < 4; ++n)
            bfr[n] = *(const bf16x8*)&Bs[(wn * 64 + n * 16 + l15) * LDP + l4 * 8];
#pragma unroll
        for (int m = 0; m < 4; ++m)
#pragma unroll
            for (int n = 0; n < 4; ++n)
                acc[m][n] = __builtin_amdgcn_mfma_f32_16x16x32_bf16(bfr[n], afr[m], acc[m][n], 0, 0, 0);
        __syncthreads();
    }
    // swapped operands => lane holds C[row = l15][cols = l4*4 + 0..3]
#pragma unroll
    for (int m = 0; m < 4; ++m) {
        long row = (long)bm * 128 + wm * 64 + m * 16 + l15;
        if (row < N_NODES) {
#pragma unroll
            for (int n = 0; n < 4; ++n) {
                int colb = bn * 128 + wn * 64 + n * 16 + l4 * 4;
                ushort4 o;
                o.x = f2bf(acc[m][n][0]);
                o.y = f2bf(acc[m][n][1]);
                o.z = f2bf(acc[m][n][2]);
                o.w = f2bf(acc[m][n][3]);
                *(ushort4*)&support[row * NHID + colb] = o;
            }
        }
    }
}

// ---------------- SpMM1 + bias + ReLU -> h (bf16). one wave per row ----------------
__global__ __launch_bounds__(256) void k_spmm1(const int* __restrict__ rowptr, const int* __restrict__ pcol,
                                               const float* __restrict__ pval,
                                               const unsigned short* __restrict__ support,
                                               const float* __restrict__ b1, unsigned short* __restrict__ h) {
    int wrow = (blockIdx.x * 256 + threadIdx.x) >> 6;
    int lane = threadIdx.x & 63;
    if (wrow >= N_NODES) return;
    int beg = rowptr[wrow], end = rowptr[wrow + 1];
    float a0 = 0.f, a1 = 0.f, a2 = 0.f, a3 = 0.f;
    int c4 = lane * 4;
    for (int e = beg; e < end; ++e) {
        int c = pcol[e];
        float v = pval[e];
        uint2 raw = *(const uint2*)&support[(long)c * NHID + c4];
        a0 = fmaf(v, bflo(raw.x), a0);
        a1 = fmaf(v, bfhi(raw.x), a1);
        a2 = fmaf(v, bflo(raw.y), a2);
        a3 = fmaf(v, bfhi(raw.y), a3);
    }
    a0 = fmaxf(a0 + b1[c4 + 0], 0.f);
    a1 = fmaxf(a1 + b1[c4 + 1], 0.f);
    a2 = fmaxf(a2 + b1[c4 + 2], 0.f);
    a3 = fmaxf(a3 + b1[c4 + 3], 0.f);
    ushort4 o;
    o.x = f2bf(a0); o.y = f2bf(a1); o.z = f2bf(a2); o.w = f2bf(a3);
    *(ushort4*)&h[(long)wrow * NHID + c4] = o;
}

// ---------------- GEMM2: logits2 = h @ W2 (fp32 out) ----------------
__global__ __launch_bounds__(256) void k_gemm2(const unsigned short* __restrict__ H,
                                               const unsigned short* __restrict__ W2T,
                                               float* __restrict__ logits2) {
    __shared__ unsigned short As[128 * LDP];
    __shared__ unsigned short Bs[64 * LDP];
    const int t = threadIdx.x;
    const int lane = t & 63;
    const int w = t >> 6;
    const int wm = w >> 1, wn = w & 1;
    const int l15 = lane & 15, l4 = lane >> 4;
    const int bm = blockIdx.x;

    f32x4 acc[4][2];
#pragma unroll
    for (int m = 0; m < 4; ++m)
#pragma unroll
        for (int n = 0; n < 2; ++n) acc[m][n] = (f32x4){0.f, 0.f, 0.f, 0.f};

    const int srow = t >> 1, shalf = t & 1;
    const long grow = (long)bm * 128 + srow;
    const bool avalid = grow < N_NODES;
    const unsigned short* asrc = H + grow * NHID + shalf * 16;
    const int bn2 = t >> 2, bq = t & 3;
    const unsigned short* bsrc = W2T + bn2 * NHID + bq * 8;

    for (int kt = 0; kt < NHID; kt += 32) {
        uint4 a0, a1;
        if (avalid) {
            a0 = *(const uint4*)(asrc + kt);
            a1 = *(const uint4*)(asrc + kt + 8);
        } else {
            a0 = make_uint4(0, 0, 0, 0);
            a1 = make_uint4(0, 0, 0, 0);
        }
        uint4 bv = *(const uint4*)(bsrc + kt);
        *(uint4*)&As[srow * LDP + shalf * 16] = a0;
        *(uint4*)&As[srow * LDP + shalf * 16 + 8] = a1;
        *(uint4*)&Bs[bn2 * LDP + bq * 8] = bv;
        __syncthreads();

        bf16x8 afr[4], bfr[2];
#pragma unroll
        for (int m = 0; m < 4; ++m)
            afr[m] = *(const bf16x8*)&As[(wm * 64 + m * 16 + l15) * LDP + l4 * 8];
#pragma unroll
        for (int n = 0; n < 2; ++n)
            bfr[n] = *(const bf16x8*)&Bs[(wn * 32 + n * 16 + l15) * LDP + l4 * 8];
#pragma unroll
        for (int m = 0; m < 4; ++m)
#pragma unroll
            for (int n = 0; n < 2; ++n)
                acc[m][n] = __builtin_amdgcn_mfma_f32_16x16x32_bf16(bfr[n], afr[m], acc[m][n], 0, 0, 0);
        __syncthreads();
    }
#pragma unroll
    for (int m = 0; m < 4; ++m) {
        long row = (long)bm * 128 + wm * 64 + m * 16 + l15;
        if (row < N_NODES) {
#pragma unroll
            for (int n = 0; n < 2; ++n) {
                int colb = wn * 32 + n * 16 + l4 * 4;
                if (colb < NCLASS)
                    *(f32x4*)&logits2[row * NCLASS + colb] = acc[m][n];
            }
        }
    }
}

// ---------------- SpMM2 + bias + log_softmax -> out (fp32). one wave per row ----------------
__global__ __launch_bounds__(256) void k_spmm2(const int* __restrict__ rowptr, const int* __restrict__ pcol,
                                               const float* __restrict__ pval,
                                               const float* __restrict__ logits2,
                                               const float* __restrict__ b2, float* __restrict__ out) {
    int wrow = (blockIdx.x * 256 + threadIdx.x) >> 6;
    int lane = threadIdx.x & 63;
    if (wrow >= N_NODES) return;
    int beg = rowptr[wrow], end = rowptr[wrow + 1];
    bool act = lane < NCLASS;
    int colidx = act ? lane : 0;
    float acc = 0.f;
    for (int e = beg; e < end; ++e) {
        int c = pcol[e];
        float v = pval[e];
        float g = logits2[(long)c * NCLASS + colidx];
        acc = fmaf(v, g, acc);
    }
    acc += b2[colidx];
    float mv = act ? acc : -INFINITY;
#pragma unroll
    for (int off = 32; off; off >>= 1) mv = fmaxf(mv, __shfl_xor(mv, off, 64));
    float p = act ? __expf(acc - mv) : 0.f;
    float s = p;
#pragma unroll
    for (int off = 32; off; off >>= 1) s += __shfl_xor(s, off, 64);
    if (act) out[(long)wrow * NCLASS + lane] = acc - mv - __logf(s);
}

extern "C" void kernel_launch(void* const* d_in, const int* in_sizes, int n_in,
                              void* d_out, int out_size, void* d_ws, size_t ws_size,
                              hipStream_t stream) {
    const float* x    = (const float*)d_in[0];
    const int*   erow = (const int*)d_in[1];
    const int*   ecol = (const int*)d_in[2];
    const float* eval_ = (const float*)d_in[3];
    const float* W1   = (const float*)d_in[4];
    const float* b1   = (const float*)d_in[5];
    const float* W2   = (const float*)d_in[6];
    const float* b2   = (const float*)d_in[7];
    float* out = (float*)d_out;

    char* p = (char*)d_ws;
    auto alloc = [&](size_t b) { char* r = p; p += (b + 255) & ~(size_t)255; return r; };
    int* counts            = (int*)alloc((size_t)N_NODES * 4);
    int* rowptr            = (int*)alloc((size_t)(N_NODES + 1) * 4);
    int* cursor            = (int*)alloc((size_t)N_NODES * 4);
    int* bsums             = (int*)alloc(512);
    int* pcol              = (int*)alloc((size_t)N_EDGES * 4);
    float* pval            = (float*)alloc((size_t)N_EDGES * 4);
    unsigned short* W1T    = (unsigned short*)alloc((size_t)NHID * NFEAT * 2);
    unsigned short* W2T    = (unsigned short*)alloc((size_t)64 * NHID * 2);
    unsigned short* support= (unsigned short*)alloc((size_t)N_NODES * NHID * 2);
    unsigned short* h      = (unsigned short*)alloc((size_t)N_NODES * NHID * 2);
    float* logits2         = (float*)alloc((size_t)N_NODES * NCLASS * 4);

    hipMemsetAsync(counts, 0, (size_t)N_NODES * 4, stream);
    k_hist<<<(N_EDGES + 255) / 256, 256, 0, stream>>>(erow, counts, N_EDGES);
    k_scanA<<<98, 256, 0, stream>>>(counts, rowptr, bsums, N_NODES);
    k_scanB<<<1, 128, 0, stream>>>(bsums, rowptr, 98, N_NODES);
    k_scanC<<<98, 256, 0, stream>>>(rowptr, cursor, bsums, N_NODES);
    k_scatter<<<(N_EDGES + 255) / 256, 256, 0, stream>>>(erow, ecol, eval_, cursor, pcol, pval, N_EDGES);
    k_w1t<<<(NHID * NFEAT) / 256, 256, 0, stream>>>(W1, W1T);
    k_w2t<<<(64 * NHID) / 256, 256, 0, stream>>>(W2, W2T);
    k_gemm1<<<dim3((N_NODES + 127) / 128, NHID / 128), 256, 0, stream>>>(x, W1T, support);
    k_spmm1<<<(N_NODES + 3) / 4, 256, 0, stream>>>(rowptr, pcol, pval, support, b1, h);
    k_gemm2<<<(N_NODES + 127) / 128, 256, 0, stream>>>(h, W2T, logits2);
    k_spmm2<<<(N_NODES + 3) / 4, 256, 0, stream>>>(rowptr, pcol, pval, logits2, b2, out);
}